// Round 8
// baseline (263.063 us; speedup 1.0000x reference)
//
#include <hip/hip_runtime.h>

// IndexNSW R12: distributed fill across 4 waves, LDS-flag sync (intra-CU).
// B=64 blocks x 256 threads; wave 0 = coordinator (search state, merge,
// pick — byte-identical to R4/R9), waves 0..3 each fill+score 8 of the 32
// candidate rows per step.
//
// Why: R4==R7 (5400cy fill under 8x transaction regrouping) => fill is
// outstanding-line-window bound. R11 (helper touch waves) was ~neutral BUT
// main's window was compiler-shrunk 3x (VGPR 144->88) => helpers must have
// added concurrency => window is likely PER-WAVE. This kernel gives each
// wave its own 64-line window via line-per-lane loads (lane l: row l>>3,
// line l&7, 8 float4 = only 32 staging VGPRs; first load instr puts all 64
// lines of the wave in flight). Sync is LDS acquire/release flags (~100cy),
// NOT R8's agent-scope coherence-point atomics (~900cy polls).
//
// Bit-exactness: each (row,half) distance partial is one lane's sequential
// 32-step fmaf chain over the same chunks in the same order as R4 (rows
// staged via LDS; f32 round trip exact), combined with the same
// __shfl_xor(32) add. Freshness, merge keys, pick, output: byte-identical
// in wave 0. => trajectory and output bit-identical (absmax 0.0).
// Merge key = (f32 bits of d)<<6 | concat idx == lax.top_k stable order.
//
// Protocol per step s (sig = ((s+1)<<1)|mode, monotonic):
//   wave0: publish sig (mode1: pub_ids[] = ids, from old-cand graph
//          prefetch; mode0: uidsh = u, waves load graph themselves)
//   all:   ids -> fill 8 rows (64 lines) -> stage to own LDS region ->
//          16 lanes compute 8 distances -> dvals[] -> done++ (release)
//   wave0: spin done==4(s+1) (acquire) -> freshness-mask -> merge -> pick
//          -> old-cand gpre for next step -> publish next sig.
// Helpers only read pub_ids/uidsh after acquiring sig; wave0 only reads
// dvals after acquiring done => no races. done monotonic => no ABA.

#define DIMS    256
#define RDEG    32
#define EFPOOL  32
#define KOUT    10
#define NWORDS  3125     // ceil(100000 / 32)
#define INF_D   1e30f
#define RSTRIDE 65       // float4 stride per staged row (64 + 1 pad)

typedef unsigned long long u64;

__global__ __launch_bounds__(256, 1) void nsw_mw_kernel(
    const float* __restrict__ query,    // [B, 256]
    const float* __restrict__ storage,  // [N, 256]
    const int*   __restrict__ graph,    // [N, 32]
    const int*   __restrict__ initial,  // [B, 32]
    float*       __restrict__ out,      // [B*10 ids as float][B*10 dists]
    int B)
{
    __shared__ unsigned int visited[NWORDS];
    __shared__ unsigned int expanded[NWORDS];
    __shared__ float4 qsh[DIMS / 4];            // query row, 64 float4
    __shared__ float4 ldsrows[4][8 * RSTRIDE];  // per-wave 8-row staging
    __shared__ u64    keys[64];                 // merge keys
    __shared__ float  sc_d[EFPOOL];             // merge scatter scratch
    __shared__ int    sc_id[EFPOOL];
    __shared__ int    pub_ids[EFPOOL];          // ids published on mode1
    __shared__ float  dvals[EFPOOL];            // raw distances per slot
    __shared__ int    sig;                      // ((s+1)<<1)|mode
    __shared__ int    uidsh;                    // u for mode0
    __shared__ int    done;                     // monotonic wave-done counter

    const int t    = threadIdx.x;   // 0..255
    const int wv   = t >> 6;        // wave 0 = coordinator
    const int l    = t & 63;
    const int b    = blockIdx.x;
    const int nb   = l & 31;        // pool/cand slot owned (dup across halves)
    const int half = l >> 5;        // 128-dim half for distance duty
    const int fr   = l >> 3;        // fill duty: row 0..7 within wave's group
    const int fl   = l & 7;         // fill duty: 128B line 0..7 of that row
    const int cr   = l & 7;         // compute duty: row (lanes nb<8 active)
    const bool act = (nb < 8);      // compute-duty lanes: 0..7 and 32..39

    for (int i = t; i < NWORDS; i += 256) { visited[i] = 0u; expanded[i] = 0u; }
    if (t == 0) { sig = 0; done = 0; }
    if (wv == 0)
        qsh[l] = reinterpret_cast<const float4*>(query + (size_t)b * DIMS)[l];
    __syncthreads();                // sole barrier; steps use LDS flags

    if (wv != 0) {
        // ================= helper waves: fill + score 8 rows/step =========
        for (int s = 0; s <= EFPOOL; ++s) {
            int v;
            do {
                v = __hip_atomic_load(&sig, __ATOMIC_ACQUIRE,
                                      __HIP_MEMORY_SCOPE_WORKGROUP);
            } while ((v >> 1) != s + 1);
            int gid;
            if (v & 1) gid = pub_ids[wv * 8 + fr];                    // mode1
            else       gid = graph[(size_t)uidsh * RDEG + wv * 8 + fr]; // mode0

            const float4* sp = reinterpret_cast<const float4*>(
                storage + (size_t)gid * DIMS);
            float4 rr[8];
            #pragma unroll
            for (int k = 0; k < 8; ++k) rr[k] = sp[fl * 8 + k];  // 64 lines/wave
            #pragma unroll
            for (int k = 0; k < 8; ++k)
                ldsrows[wv][fr * RSTRIDE + fl * 8 + k] = rr[k];

            // distance: R4's exact per-(row,half) chain (16 active lanes)
            float a0 = 0.f, a1 = 0.f, a2 = 0.f, a3 = 0.f;
            if (act) {
                #pragma unroll
                for (int j = 0; j < 32; ++j) {
                    float4 rv = ldsrows[wv][cr * RSTRIDE + half * 32 + j];
                    float4 qv = qsh[half * 32 + j];
                    float d0 = rv.x - qv.x; a0 = fmaf(d0, d0, a0);
                    float d1 = rv.y - qv.y; a1 = fmaf(d1, d1, a1);
                    float d2 = rv.z - qv.z; a2 = fmaf(d2, d2, a2);
                    float d3 = rv.w - qv.w; a3 = fmaf(d3, d3, a3);
                }
            }
            float part = (a0 + a1) + (a2 + a3);
            float dd = part + __shfl_xor(part, 32, 64);   // halves pair up
            if (l < 8) dvals[wv * 8 + cr] = dd;
            if (l == 0)
                __hip_atomic_fetch_add(&done, 1, __ATOMIC_RELEASE,
                                       __HIP_MEMORY_SCOPE_WORKGROUP);
        }
        return;
    }

    // ================= wave 0: coordinator + rows 0..7 ====================
    float pool_d  = INF_D;   // dummy pool; first merge sorts real entries in
    int   pool_id = 0;
    int   u       = 0;
    int   nbid    = initial[b * EFPOOL + nb];   // slot-nb id (halves dup)

    // reference marks all initial ids visited before the scan
    if (l < 32) atomicOr(&visited[nbid >> 5], 1u << (nbid & 31));

    // publish step 0 (mode1: ids are the initial pool)
    if (l < 32) pub_ids[nb] = nbid;
    if (l == 0) uidsh = 0;
    __hip_atomic_store(&sig, (1 << 1) | 1, __ATOMIC_RELEASE,
                       __HIP_MEMORY_SCOPE_WORKGROUP);

    for (int s = 0; s <= EFPOOL; ++s) {
        // ---- fill own rows 0..7 (issue first: 64 lines in flight) ----
        int gid = __shfl(nbid, fr, 64);          // id of slot fr
        const float4* sp = reinterpret_cast<const float4*>(
            storage + (size_t)gid * DIMS);
        float4 rr[8];
        #pragma unroll
        for (int k = 0; k < 8; ++k) rr[k] = sp[fl * 8 + k];

        // ---- hidden under fill: expanded mark, freshness, old-cand ----
        if (s > 0 && l == 0) expanded[u >> 5] |= 1u << (u & 31);  // sole writer
        bool fresh = true;
        if (s > 0) {
            unsigned vw = visited[nbid >> 5];    // read-all precedes OR: dup-safe
            fresh = !((vw >> (nbid & 31)) & 1u);
            if ((l < 32) && fresh) atomicOr(&visited[nbid >> 5], 1u << (nbid & 31));
        }
        // old candidate = first unexpanded slot of current (pre-merge) pool
        bool ounexp = !((expanded[pool_id >> 5] >> (pool_id & 31)) & 1u);
        u64  obm    = __ballot(ounexp && (l < 32));
        int  oslot  = (obm == 0ull) ? 0 : (__ffsll(obm) - 1);
        int  old_id = __shfl(pool_id, oslot, 64);
        int  gpre   = 0;
        if (s < EFPOOL)                          // old-cand graph prefetch
            gpre = graph[(size_t)old_id * RDEG + nb];

        // ---- stage own rows; compute own 8 distances (exact chain) ----
        #pragma unroll
        for (int k = 0; k < 8; ++k)
            ldsrows[0][fr * RSTRIDE + fl * 8 + k] = rr[k];
        float a0 = 0.f, a1 = 0.f, a2 = 0.f, a3 = 0.f;
        if (act) {
            #pragma unroll
            for (int j = 0; j < 32; ++j) {
                float4 rv = ldsrows[0][cr * RSTRIDE + half * 32 + j];
                float4 qv = qsh[half * 32 + j];
                float d0 = rv.x - qv.x; a0 = fmaf(d0, d0, a0);
                float d1 = rv.y - qv.y; a1 = fmaf(d1, d1, a1);
                float d2 = rv.z - qv.z; a2 = fmaf(d2, d2, a2);
                float d3 = rv.w - qv.w; a3 = fmaf(d3, d3, a3);
            }
        }
        float part = (a0 + a1) + (a2 + a3);
        float dd = part + __shfl_xor(part, 32, 64);
        if (l < 8) dvals[cr] = dd;
        if (l == 0)
            __hip_atomic_fetch_add(&done, 1, __ATOMIC_RELEASE,
                                   __HIP_MEMORY_SCOPE_WORKGROUP);

        // ---- collect all 32 distances ----
        while (__hip_atomic_load(&done, __ATOMIC_ACQUIRE,
                                 __HIP_MEMORY_SCOPE_WORKGROUP) < 4 * (s + 1)) {}
        float dm = dvals[nb];                    // raw d of slot nb
        float nd = fresh ? dm : INF_D;           // same masking as R4

        // ---- merge: 64 concat elems -> sorted top-32 (byte-identical R4) ----
        {
            float ed  = half ? nd   : pool_d;
            int   eid = half ? nbid : pool_id;
            u64 key = ((u64)__float_as_uint(ed) << 6) | (unsigned)l;
            keys[l] = key;
            int rank = 0;
            #pragma unroll
            for (int j = 0; j < 64; ++j)            // same addr all lanes: broadcast
                rank += (keys[j] < key) ? 1 : 0;
            if (rank < EFPOOL) { sc_d[rank] = ed; sc_id[rank] = eid; }  // unique
            pool_d  = sc_d[nb];                     // in-order DS: no barrier
            pool_id = sc_id[nb];
        }

        // ---- pick next u; publish next step ----
        if (s < EFPOOL) {
            bool unexp = !((expanded[pool_id >> 5] >> (pool_id & 31)) & 1u);
            u64 bm = __ballot(unexp && (l < 32));
            int slot = (bm == 0ull) ? 0 : (__ffsll(bm) - 1);
            int utrue = sc_id[slot];                // uniform: broadcast read
            bool m1 = (__builtin_amdgcn_readfirstlane(utrue) ==
                       __builtin_amdgcn_readfirstlane(old_id));
            u = utrue;
            if (m1) {
                nbid = gpre;                        // ids already on hand
                if (l < 32) pub_ids[nb] = nbid;
                __hip_atomic_store(&sig, ((s + 2) << 1) | 1, __ATOMIC_RELEASE,
                                   __HIP_MEMORY_SCOPE_WORKGROUP);
            } else {
                if (l == 0) uidsh = utrue;
                __hip_atomic_store(&sig, ((s + 2) << 1) | 0, __ATOMIC_RELEASE,
                                   __HIP_MEMORY_SCOPE_WORKGROUP);
                nbid = graph[(size_t)utrue * RDEG + nb];   // parallel w/ helpers
            }
        }
    }

    // ---- output: pool sorted ascending; ids as float (exact < 2^24) ----
    if (l < KOUT) {
        out[b * KOUT + l]            = (float)pool_id;
        out[B * KOUT + b * KOUT + l] = pool_d;
    }
}

extern "C" void kernel_launch(void* const* d_in, const int* in_sizes, int n_in,
                              void* d_out, int out_size, void* d_ws, size_t ws_size,
                              hipStream_t stream) {
    const float* query   = (const float*)d_in[0];
    const float* storage = (const float*)d_in[1];
    const int*   graph   = (const int*)d_in[2];
    const int*   initial = (const int*)d_in[3];
    float* out = (float*)d_out;

    const int B = in_sizes[0] / DIMS;   // 64

    nsw_mw_kernel<<<B, 256, 0, stream>>>(query, storage, graph, initial, out, B);
}

// Round 9
// 230.134 us; speedup vs baseline: 1.1431x; 1.1431x over previous
//
#include <hip/hip_runtime.h>

// IndexNSW R13: deferred-merge software pipeline. One WAVE per query
// (B=64 blocks x 64 threads), zero barriers (single-wave lockstep).
//
// Established: fill = 256 lines vs ~43-line PER-CU window ~= 5400cy floor
// (R4==R7: transaction grouping irrelevant; R12: multi-wave private windows
// don't help; R8: cross-CU split loses to agent-scope sync). Remaining
// target = R9's ~1700cy exposed tail.
//
// Proven this round: the union-min speculative pick is ALWAYS the exact
// reference pick: min by (d, concat-idx) over {unexpanded old pool} U
// {fresh news} equals argmin over the merged top-32 (strict-order argument),
// and the all-expanded corner is patched exactly: if no unexpanded pool
// entry, ref picks pool[0] unless best-fresh strictly beats pool[31]
// (fresh concat-idx > old => enters top-32 iff d_new < d_31). So the merge
// is NOT needed for the pick => defer merge(s) + expanded-mark + old-cand
// ballot + gpre prefetch of step s under step s+1's fill. Exposed tail =
// dist-tail + 5-shfl spec reduce + select + (graph iff fresh wins) + issue.
//
// Numerics: dist fmaf chain, merge key/rank/scatter, output byte-identical
// to R4; picks proven identical => bit-identical trajectory (absmax 0.0).
// Merge key = (f32 bits of d)<<6 | concat idx == lax.top_k stable order.

#define DIMS   256
#define RDEG   32
#define EFPOOL 32
#define KOUT   10
#define NWORDS 3125     // ceil(100000 / 32)
#define INF_D  1e30f

typedef unsigned long long u64;

__global__ __launch_bounds__(64, 1) void nsw_wave_kernel(
    const float* __restrict__ query,    // [B, 256]
    const float* __restrict__ storage,  // [N, 256]
    const int*   __restrict__ graph,    // [N, 32]
    const int*   __restrict__ initial,  // [B, 32]
    float*       __restrict__ out,      // [B*10 ids as float][B*10 dists]
    int B)
{
    __shared__ unsigned int visited[NWORDS];
    __shared__ unsigned int expanded[NWORDS];
    __shared__ float4 qsh[DIMS / 4];            // query row, 64 float4
    __shared__ u64    keys[64];                 // merge keys
    __shared__ float  sc_d[EFPOOL];             // merge scatter scratch
    __shared__ int    sc_id[EFPOOL];

    const int l    = threadIdx.x;   // 0..63
    const int b    = blockIdx.x;
    const int nb   = l & 31;        // neighbor / pool slot owned (dup across halves)
    const int half = l >> 5;        // which 128-dim half this lane covers

    for (int i = l; i < NWORDS; i += 64) { visited[i] = 0u; expanded[i] = 0u; }

    // stage query row to LDS (coalesced: lane l -> float4 l)
    qsh[l] = reinterpret_cast<const float4*>(query + (size_t)b * DIMS)[l];

    float pool_d  = INF_D;   // dummy pool; first merge sorts the real entries in
    int   pool_id = 0;
    int   u       = 0;       // pick of step s-1 (marked expanded in phase A of s)
    int   nbid    = initial[b * EFPOOL + nb];   // slot-nb candidate id
    float pend_nd = INF_D;   // deferred-merge operands (step s-1 candidates)
    int   pend_nbid = 0;

    // reference marks all initial ids visited before the scan
    if (l < 32) atomicOr(&visited[nbid >> 5], 1u << (nbid & 31));

    // prologue: issue fill for the initial candidates
    float4 r[32];
    {
        const float4* sp = reinterpret_cast<const float4*>(
            storage + (size_t)nbid * DIMS) + half * 32;
        #pragma unroll
        for (int j = 0; j < 32; ++j) r[j] = sp[j];
    }

    for (int s = 0; s <= EFPOOL; ++s) {   // s==0: initial pool, then 32 expansions
        // ================= phase A: hidden under the in-flight fill ========
        if (s > 0) {
            // mark step-(s-1)'s pick expanded (sole writer; DS program order)
            if (l == 0) expanded[u >> 5] |= 1u << (u & 31);
            // deferred merge of step-(s-1) candidates (byte-identical R4)
            float ed  = half ? pend_nd   : pool_d;
            int   eid = half ? pend_nbid : pool_id;
            u64 key = ((u64)__float_as_uint(ed) << 6) | (unsigned)l;
            keys[l] = key;
            int rank = 0;
            #pragma unroll
            for (int j = 0; j < 64; ++j)            // same addr all lanes: broadcast
                rank += (keys[j] < key) ? 1 : 0;
            if (rank < EFPOOL) { sc_d[rank] = ed; sc_id[rank] = eid; }  // unique
            pool_d  = sc_d[nb];                     // in-order DS: no barrier
            pool_id = sc_id[nb];
        }

        // freshness of CURRENT candidates (read-all precedes OR: dup-safe)
        bool fresh = true;
        if (s > 0) {
            unsigned vw = visited[nbid >> 5];
            fresh = !((vw >> (nbid & 31)) & 1u);
            if ((l < 32) && fresh) atomicOr(&visited[nbid >> 5], 1u << (nbid & 31));
        }

        // old candidate: first unexpanded slot of the (current, merged) pool
        bool ounexp = !((expanded[pool_id >> 5] >> (pool_id & 31)) & 1u);
        u64  obm    = __ballot(ounexp && (l < 32));
        int  oslot  = (obm == 0ull) ? 0 : (__ffsll(obm) - 1);
        float old_d = __shfl(pool_d,  oslot, 64);
        int   old_id= __shfl(pool_id, oslot, 64);   // == pool[0] id when obm==0
        bool  old_ok= (obm != 0ull);
        float d31   = __shfl(pool_d, 31, 64);       // worst pool entry (sorted)
        int   gpre  = 0;
        if (s < EFPOOL) {
            gpre = graph[(size_t)old_id * RDEG + nb];   // prefetch, hidden
            asm volatile("" : "+v"(gpre));              // forbid sinking to use
        }

        // ================= phase B: exposed ================================
        // distance: R4's EXACT chain (compiler inserts vmcnt waits per use)
        float a0 = 0.f, a1 = 0.f, a2 = 0.f, a3 = 0.f;
        #pragma unroll
        for (int j = 0; j < 32; ++j) {
            float4 q = qsh[half * 32 + j];
            float d0 = r[j].x - q.x; a0 = fmaf(d0, d0, a0);
            float d1 = r[j].y - q.y; a1 = fmaf(d1, d1, a1);
            float d2 = r[j].z - q.z; a2 = fmaf(d2, d2, a2);
            float d3 = r[j].w - q.w; a3 = fmaf(d3, d3, a3);
        }
        float part = (a0 + a1) + (a2 + a3);
        float d  = part + __shfl_xor(part, 32, 64);   // halves share a row
        float nd = fresh ? d : INF_D;

        if (s < EFPOOL) {
            // best fresh candidate: exact min by (dbits<<6 | 32+slot);
            // 5-step reduce (lanes l and l^32 hold identical keys)
            u64 nk = fresh ? (((u64)__float_as_uint(nd) << 6) | (u64)(32 + nb))
                           : ~0ull;
            #pragma unroll
            for (int m = 1; m < 32; m <<= 1) {
                u64 o = __shfl_xor(nk, m, 64);
                nk = (o < nk) ? o : nk;
            }
            int wslot  = ((int)(nk & 63) - 32) & 31;
            int new_id = __shfl(nbid, wslot, 64);
            u64 okey = old_ok ? (((u64)__float_as_uint(old_d) << 6) | (u64)oslot)
                              : ~0ull;
            // exact pick (proof in header): old path iff old wins the union
            // order, or the all-expanded corner (best fresh fails top-32:
            // needs d_new < d31 strictly since fresh concat-idx > old; when
            // no fresh, nk>>6 truncates to NaN bits -> comparison false).
            float dnew = __uint_as_float((unsigned)(nk >> 6));
            bool oldpath = (!(nk < okey)) || (!old_ok && !(dnew < d31));
            u = oldpath ? old_id : new_id;              // wave-uniform
            int nn = oldpath ? gpre
                             : graph[(size_t)new_id * RDEG + nb];  // exposed
            pend_nd = nd; pend_nbid = nbid;             // defer merge to s+1
            nbid = nn;
            const float4* sp = reinterpret_cast<const float4*>(
                storage + (size_t)nbid * DIMS) + half * 32;
            #pragma unroll
            for (int j = 0; j < 32; ++j) r[j] = sp[j];  // next fill in flight
        } else {
            pend_nd = nd; pend_nbid = nbid;             // last candidates
        }
    }

    // final merge (step-32 candidates), byte-identical to the in-loop merge
    {
        float ed  = half ? pend_nd   : pool_d;
        int   eid = half ? pend_nbid : pool_id;
        u64 key = ((u64)__float_as_uint(ed) << 6) | (unsigned)l;
        keys[l] = key;
        int rank = 0;
        #pragma unroll
        for (int j = 0; j < 64; ++j)
            rank += (keys[j] < key) ? 1 : 0;
        if (rank < EFPOOL) { sc_d[rank] = ed; sc_id[rank] = eid; }
        pool_d  = sc_d[nb];
        pool_id = sc_id[nb];
    }

    // ---- output: pool sorted ascending; ids as float (exact < 2^24) ----
    if (l < KOUT) {
        out[b * KOUT + l]            = (float)pool_id;
        out[B * KOUT + b * KOUT + l] = pool_d;
    }
}

extern "C" void kernel_launch(void* const* d_in, const int* in_sizes, int n_in,
                              void* d_out, int out_size, void* d_ws, size_t ws_size,
                              hipStream_t stream) {
    const float* query   = (const float*)d_in[0];
    const float* storage = (const float*)d_in[1];
    const int*   graph   = (const int*)d_in[2];
    const int*   initial = (const int*)d_in[3];
    float* out = (float*)d_out;

    const int B = in_sizes[0] / DIMS;   // 64

    nsw_wave_kernel<<<B, 64, 0, stream>>>(query, storage, graph, initial, out, B);
}